// Round 1
// baseline (2995.096 us; speedup 1.0000x reference)
//
#include <hip/hip_runtime.h>

#define N_NODES 100000
#define N_EDGES 600000
#define NUM_GRAPHS 256

// ---------------------------------------------------------------------------
// Scatter-add of messages: agg[dst[e]][f] += x[src[e]][f] * w[e]
// F multiple of 4: float4-vectorized gather, scalar atomics.
// ---------------------------------------------------------------------------
template<int F>
__global__ void scatter_kernel(const int* __restrict__ src, const int* __restrict__ dst,
                               const float* __restrict__ w, const float* __restrict__ x,
                               float* __restrict__ agg, int E) {
    constexpr int C = F / 4;
    int idx = blockIdx.x * blockDim.x + threadIdx.x;
    int total = E * C;
    if (idx >= total) return;
    int e = idx / C;
    int c = idx - e * C;
    int s = src[e];
    int d = dst[e];
    float we = w[e];
    float4 v = *(reinterpret_cast<const float4*>(x + (size_t)s * F) + c);
    float* p = agg + (size_t)d * F + c * 4;
    atomicAdd(p + 0, v.x * we);
    atomicAdd(p + 1, v.y * we);
    atomicAdd(p + 2, v.z * we);
    atomicAdd(p + 3, v.w * we);
}

// F = 5 (input layer): scalar
__global__ void scatter5_kernel(const int* __restrict__ src, const int* __restrict__ dst,
                                const float* __restrict__ w, const float* __restrict__ x,
                                float* __restrict__ agg, int E) {
    int idx = blockIdx.x * blockDim.x + threadIdx.x;
    int total = E * 5;
    if (idx >= total) return;
    int e = idx / 5;
    int f = idx - e * 5;
    atomicAdd(agg + (size_t)dst[e] * 5 + f,
              x[(size_t)src[e] * 5 + f] * w[e]);
}

// ---------------------------------------------------------------------------
// out[n][j] = relu( sum_k agg[n][k]*Wrel[k][j] + brel[j] + sum_k x[n][k]*Wroot[k][j] )
// Block = 256 threads. Thread tile: 4 nodes x 4 outputs, float4 loads.
// ---------------------------------------------------------------------------
template<int FIN, int FOUT>
__global__ void conv_out_kernel(const float* __restrict__ agg, const float* __restrict__ x,
                                const float* __restrict__ Wrel, const float* __restrict__ brel,
                                const float* __restrict__ Wroot, float* __restrict__ out) {
    constexpr int JG = FOUT / 4;    // thread groups along output dim
    constexpr int NG = 256 / JG;    // node groups per block
    constexpr int NT = NG * 4;      // nodes per block
    const int tid = threadIdx.x;
    const int jg = tid % JG;
    const int ng = tid / JG;
    const int n0 = blockIdx.x * NT + ng * 4;

    float acc[4][4] = {};

    if constexpr (FIN % 4 == 0) {
        for (int k0 = 0; k0 < FIN; k0 += 4) {
            float a[4][4], xx[4][4];
            #pragma unroll
            for (int i = 0; i < 4; ++i) {
                int n = n0 + i;
                if (n < N_NODES) {
                    float4 ta = *reinterpret_cast<const float4*>(agg + (size_t)n * FIN + k0);
                    float4 tx = *reinterpret_cast<const float4*>(x   + (size_t)n * FIN + k0);
                    a[i][0] = ta.x; a[i][1] = ta.y; a[i][2] = ta.z; a[i][3] = ta.w;
                    xx[i][0] = tx.x; xx[i][1] = tx.y; xx[i][2] = tx.z; xx[i][3] = tx.w;
                } else {
                    #pragma unroll
                    for (int kk = 0; kk < 4; ++kk) { a[i][kk] = 0.f; xx[i][kk] = 0.f; }
                }
            }
            #pragma unroll
            for (int kk = 0; kk < 4; ++kk) {
                float4 wr = *reinterpret_cast<const float4*>(Wrel  + (size_t)(k0 + kk) * FOUT + jg * 4);
                float4 wo = *reinterpret_cast<const float4*>(Wroot + (size_t)(k0 + kk) * FOUT + jg * 4);
                float wrv[4] = {wr.x, wr.y, wr.z, wr.w};
                float wov[4] = {wo.x, wo.y, wo.z, wo.w};
                #pragma unroll
                for (int i = 0; i < 4; ++i) {
                    #pragma unroll
                    for (int j = 0; j < 4; ++j) {
                        acc[i][j] += a[i][kk] * wrv[j] + xx[i][kk] * wov[j];
                    }
                }
            }
        }
    } else {
        for (int k = 0; k < FIN; ++k) {
            float a[4], xx[4];
            #pragma unroll
            for (int i = 0; i < 4; ++i) {
                int n = n0 + i;
                a[i]  = (n < N_NODES) ? agg[(size_t)n * FIN + k] : 0.f;
                xx[i] = (n < N_NODES) ? x[(size_t)n * FIN + k]   : 0.f;
            }
            float4 wr = *reinterpret_cast<const float4*>(Wrel  + (size_t)k * FOUT + jg * 4);
            float4 wo = *reinterpret_cast<const float4*>(Wroot + (size_t)k * FOUT + jg * 4);
            float wrv[4] = {wr.x, wr.y, wr.z, wr.w};
            float wov[4] = {wo.x, wo.y, wo.z, wo.w};
            #pragma unroll
            for (int i = 0; i < 4; ++i) {
                #pragma unroll
                for (int j = 0; j < 4; ++j) {
                    acc[i][j] += a[i] * wrv[j] + xx[i] * wov[j];
                }
            }
        }
    }

    float4 b4 = *reinterpret_cast<const float4*>(brel + jg * 4);
    float bv[4] = {b4.x, b4.y, b4.z, b4.w};
    #pragma unroll
    for (int i = 0; i < 4; ++i) {
        int n = n0 + i;
        if (n < N_NODES) {
            #pragma unroll
            for (int j = 0; j < 4; ++j) {
                out[(size_t)n * FOUT + jg * 4 + j] = fmaxf(acc[i][j] + bv[j], 0.f);
            }
        }
    }
}

// ---------------------------------------------------------------------------
// Global mean pool: sums per graph + counts
// ---------------------------------------------------------------------------
__global__ void pool_kernel(const float* __restrict__ x, const int* __restrict__ batch,
                            float* __restrict__ pool, float* __restrict__ cnt) {
    int idx = blockIdx.x * blockDim.x + threadIdx.x;
    if (idx >= N_NODES * 32) return;
    int n = idx >> 5;
    int f = idx & 31;
    int g = batch[n];
    atomicAdd(pool + g * 32 + f, x[(size_t)n * 32 + f]);
    if (f == 0) atomicAdd(cnt + g, 1.0f);
}

// ---------------------------------------------------------------------------
// MLP head: one thread per graph
// ---------------------------------------------------------------------------
__global__ void mlp_kernel(const float* __restrict__ pool, const float* __restrict__ cnt,
                           const float* __restrict__ W0, const float* __restrict__ b0,
                           const float* __restrict__ W1, const float* __restrict__ b1,
                           const float* __restrict__ W2, const float* __restrict__ b2,
                           float* __restrict__ out) {
    int g = blockIdx.x * blockDim.x + threadIdx.x;
    if (g >= NUM_GRAPHS) return;
    float c = fmaxf(cnt[g], 1.0f);
    float h0[32];
    #pragma unroll
    for (int f = 0; f < 32; ++f) h0[f] = pool[g * 32 + f] / c;
    float h1[32];
    for (int j = 0; j < 32; ++j) {
        float s = b0[j];
        for (int k = 0; k < 32; ++k) s += h0[k] * W0[k * 32 + j];
        h1[j] = fmaxf(s, 0.f);
    }
    float h2[16];
    for (int j = 0; j < 16; ++j) {
        float s = b1[j];
        for (int k = 0; k < 32; ++k) s += h1[k] * W1[k * 16 + j];
        h2[j] = fmaxf(s, 0.f);
    }
    float s = b2[0];
    for (int k = 0; k < 16; ++k) s += h2[k] * W2[k];
    out[g] = s;
}

// ---------------------------------------------------------------------------
extern "C" void kernel_launch(void* const* d_in, const int* in_sizes, int n_in,
                              void* d_out, int out_size, void* d_ws, size_t ws_size,
                              hipStream_t stream) {
    const float* x_in  = (const float*)d_in[0];
    const int*   ei    = (const int*)d_in[1];
    const int*   src   = ei;              // edge_index[0]
    const int*   dst   = ei + N_EDGES;    // edge_index[1]
    const float* ew    = (const float*)d_in[2];
    const int*   batch = (const int*)d_in[3];

    const float* Wrel[5]  = {(const float*)d_in[4],  (const float*)d_in[7],  (const float*)d_in[10],
                             (const float*)d_in[13], (const float*)d_in[16]};
    const float* brel[5]  = {(const float*)d_in[5],  (const float*)d_in[8],  (const float*)d_in[11],
                             (const float*)d_in[14], (const float*)d_in[17]};
    const float* Wroot[5] = {(const float*)d_in[6],  (const float*)d_in[9],  (const float*)d_in[12],
                             (const float*)d_in[15], (const float*)d_in[18]};
    const float* mW0 = (const float*)d_in[19];
    const float* mb0 = (const float*)d_in[20];
    const float* mW1 = (const float*)d_in[21];
    const float* mb1 = (const float*)d_in[22];
    const float* mW2 = (const float*)d_in[23];
    const float* mb2 = (const float*)d_in[24];

    float* ws = (float*)d_ws;
    float* A  = ws;                               // [N,128] agg buffer
    float* B  = A + (size_t)N_NODES * 128;        // [N,128]
    float* C  = B + (size_t)N_NODES * 128;        // [N,64]
    float* pool = C + (size_t)N_NODES * 64;       // [256,32]
    float* cnt  = pool + NUM_GRAPHS * 32;         // [256]

    const int BS = 256;
    auto blocks = [](long long total, int bs) { return (int)((total + bs - 1) / bs); };

    // ---- Layer 0: 5 -> 32, x = x_in, agg = A, out = B
    hipMemsetAsync(A, 0, (size_t)N_NODES * 5 * 4, stream);
    scatter5_kernel<<<blocks((long long)N_EDGES * 5, BS), BS, 0, stream>>>(src, dst, ew, x_in, A, N_EDGES);
    conv_out_kernel<5, 32><<<blocks(N_NODES, 128), BS, 0, stream>>>(A, x_in, Wrel[0], brel[0], Wroot[0], B);

    // ---- Layer 1: 32 -> 64, x = B, agg = A, out = C
    hipMemsetAsync(A, 0, (size_t)N_NODES * 32 * 4, stream);
    scatter_kernel<32><<<blocks((long long)N_EDGES * 8, BS), BS, 0, stream>>>(src, dst, ew, B, A, N_EDGES);
    conv_out_kernel<32, 64><<<blocks(N_NODES, 64), BS, 0, stream>>>(A, B, Wrel[1], brel[1], Wroot[1], C);

    // ---- Layer 2: 64 -> 128, x = C, agg = A, out = B
    hipMemsetAsync(A, 0, (size_t)N_NODES * 64 * 4, stream);
    scatter_kernel<64><<<blocks((long long)N_EDGES * 16, BS), BS, 0, stream>>>(src, dst, ew, C, A, N_EDGES);
    conv_out_kernel<64, 128><<<blocks(N_NODES, 32), BS, 0, stream>>>(A, C, Wrel[2], brel[2], Wroot[2], B);

    // ---- Layer 3: 128 -> 64, x = B, agg = A, out = C
    hipMemsetAsync(A, 0, (size_t)N_NODES * 128 * 4, stream);
    scatter_kernel<128><<<blocks((long long)N_EDGES * 32, BS), BS, 0, stream>>>(src, dst, ew, B, A, N_EDGES);
    conv_out_kernel<128, 64><<<blocks(N_NODES, 64), BS, 0, stream>>>(A, B, Wrel[3], brel[3], Wroot[3], C);

    // ---- Layer 4: 64 -> 32, x = C, agg = A, out = B
    hipMemsetAsync(A, 0, (size_t)N_NODES * 64 * 4, stream);
    scatter_kernel<64><<<blocks((long long)N_EDGES * 16, BS), BS, 0, stream>>>(src, dst, ew, C, A, N_EDGES);
    conv_out_kernel<64, 32><<<blocks(N_NODES, 128), BS, 0, stream>>>(A, C, Wrel[4], brel[4], Wroot[4], B);

    // ---- Mean pool + MLP
    hipMemsetAsync(pool, 0, (NUM_GRAPHS * 32 + NUM_GRAPHS) * 4, stream);
    pool_kernel<<<blocks((long long)N_NODES * 32, BS), BS, 0, stream>>>(B, batch, pool, cnt);
    mlp_kernel<<<1, 256, 0, stream>>>(pool, cnt, mW0, mb0, mW1, mb1, mW2, mb2, (float*)d_out);
}

// Round 2
// 968.613 us; speedup vs baseline: 3.0921x; 3.0921x over previous
//
#include <hip/hip_runtime.h>

#define N_NODES 100000
#define N_EDGES 600000
#define NUM_GRAPHS 256

// ===========================================================================
// CSR build: histogram -> scan -> fill (done once per launch, reused 5x)
// ===========================================================================
__global__ void hist_kernel(const int* __restrict__ dst, int* __restrict__ deg) {
    int e = blockIdx.x * blockDim.x + threadIdx.x;
    if (e < N_EDGES) atomicAdd(&deg[dst[e]], 1);
}

// Single-block exclusive scan of deg[N] -> rowptr[N+1]
__global__ void scan_kernel(const int* __restrict__ deg, int* __restrict__ rowptr) {
    __shared__ int part[1024];
    const int t = threadIdx.x;
    const int CH = (N_NODES + 1023) / 1024;
    int lo = t * CH, hi = min(lo + CH, N_NODES);
    int s = 0;
    for (int i = lo; i < hi; ++i) s += deg[i];
    part[t] = s;
    __syncthreads();
    // inclusive scan (Hillis-Steele)
    for (int off = 1; off < 1024; off <<= 1) {
        int v = (t >= off) ? part[t - off] : 0;
        __syncthreads();
        part[t] += v;
        __syncthreads();
    }
    int base = (t == 0) ? 0 : part[t - 1];
    for (int i = lo; i < hi; ++i) { rowptr[i] = base; base += deg[i]; }
    if (t == 1023) rowptr[N_NODES] = part[1023];
}

__global__ void copy_kernel(const int* __restrict__ a, int* __restrict__ b, int n) {
    int i = blockIdx.x * blockDim.x + threadIdx.x;
    if (i < n) b[i] = a[i];
}

__global__ void fill_kernel(const int* __restrict__ src, const int* __restrict__ dst,
                            const float* __restrict__ w, int* __restrict__ cursor,
                            int* __restrict__ ssrc, float* __restrict__ sw) {
    int e = blockIdx.x * blockDim.x + threadIdx.x;
    if (e >= N_EDGES) return;
    int pos = atomicAdd(&cursor[dst[e]], 1);
    ssrc[pos] = src[e];
    sw[pos] = w[e];
}

// ===========================================================================
// CSR gather-aggregate: out[n] = sum_{e in in(n)} y[src_e] * w_e
// F/4 lanes per node, float4 loads. FUSED: out = relu(acc + r[n] + b)
// ===========================================================================
template<int F, bool FUSED>
__global__ void gather_kernel(const int* __restrict__ rowptr, const int* __restrict__ ssrc,
                              const float* __restrict__ sw, const float* __restrict__ y,
                              const float* __restrict__ r, const float* __restrict__ b,
                              float* __restrict__ out) {
    constexpr int G = F / 4;
    constexpr int NPB = 256 / G;
    const int tid = threadIdx.x;
    const int c = tid % G;
    const int ln = tid / G;
    const int n = blockIdx.x * NPB + ln;
    if (n >= N_NODES) return;
    const int beg = rowptr[n], end = rowptr[n + 1];
    float4 acc = {0.f, 0.f, 0.f, 0.f};
    for (int i = beg; i < end; ++i) {
        int s = ssrc[i];
        float we = sw[i];
        float4 v = *(reinterpret_cast<const float4*>(y + (size_t)s * F) + c);
        acc.x += v.x * we; acc.y += v.y * we; acc.z += v.z * we; acc.w += v.w * we;
    }
    if constexpr (FUSED) {
        float4 rv = *(reinterpret_cast<const float4*>(r + (size_t)n * F) + c);
        float4 bv = *(reinterpret_cast<const float4*>(b) + c);
        acc.x = fmaxf(acc.x + rv.x + bv.x, 0.f);
        acc.y = fmaxf(acc.y + rv.y + bv.y, 0.f);
        acc.z = fmaxf(acc.z + rv.z + bv.z, 0.f);
        acc.w = fmaxf(acc.w + rv.w + bv.w, 0.f);
    }
    *(reinterpret_cast<float4*>(out + (size_t)n * F) + c) = acc;
}

// width-5 input layer: one thread per node
__global__ void gather5_kernel(const int* __restrict__ rowptr, const int* __restrict__ ssrc,
                               const float* __restrict__ sw, const float* __restrict__ x,
                               float* __restrict__ agg) {
    int n = blockIdx.x * blockDim.x + threadIdx.x;
    if (n >= N_NODES) return;
    float a0 = 0.f, a1 = 0.f, a2 = 0.f, a3 = 0.f, a4 = 0.f;
    for (int i = rowptr[n]; i < rowptr[n + 1]; ++i) {
        int s = ssrc[i];
        float we = sw[i];
        const float* xs = x + (size_t)s * 5;
        a0 += xs[0] * we; a1 += xs[1] * we; a2 += xs[2] * we;
        a3 += xs[3] * we; a4 += xs[4] * we;
    }
    float* o = agg + (size_t)n * 5;
    o[0] = a0; o[1] = a1; o[2] = a2; o[3] = a3; o[4] = a4;
}

// ===========================================================================
// out[n][j] = relu( agg[n]@Wrel + brel + x[n]@Wroot )  -- 4 nodes x 4 outs/thread
// ===========================================================================
template<int FIN, int FOUT>
__global__ void conv_out_kernel(const float* __restrict__ agg, const float* __restrict__ x,
                                const float* __restrict__ Wrel, const float* __restrict__ brel,
                                const float* __restrict__ Wroot, float* __restrict__ out) {
    constexpr int JG = FOUT / 4;
    constexpr int NG = 256 / JG;
    constexpr int NT = NG * 4;
    const int tid = threadIdx.x;
    const int jg = tid % JG;
    const int ng = tid / JG;
    const int n0 = blockIdx.x * NT + ng * 4;

    float acc[4][4] = {};

    if constexpr (FIN % 4 == 0) {
        for (int k0 = 0; k0 < FIN; k0 += 4) {
            float a[4][4], xx[4][4];
            #pragma unroll
            for (int i = 0; i < 4; ++i) {
                int n = n0 + i;
                if (n < N_NODES) {
                    float4 ta = *reinterpret_cast<const float4*>(agg + (size_t)n * FIN + k0);
                    float4 tx = *reinterpret_cast<const float4*>(x   + (size_t)n * FIN + k0);
                    a[i][0] = ta.x; a[i][1] = ta.y; a[i][2] = ta.z; a[i][3] = ta.w;
                    xx[i][0] = tx.x; xx[i][1] = tx.y; xx[i][2] = tx.z; xx[i][3] = tx.w;
                } else {
                    #pragma unroll
                    for (int kk = 0; kk < 4; ++kk) { a[i][kk] = 0.f; xx[i][kk] = 0.f; }
                }
            }
            #pragma unroll
            for (int kk = 0; kk < 4; ++kk) {
                float4 wr = *reinterpret_cast<const float4*>(Wrel  + (size_t)(k0 + kk) * FOUT + jg * 4);
                float4 wo = *reinterpret_cast<const float4*>(Wroot + (size_t)(k0 + kk) * FOUT + jg * 4);
                float wrv[4] = {wr.x, wr.y, wr.z, wr.w};
                float wov[4] = {wo.x, wo.y, wo.z, wo.w};
                #pragma unroll
                for (int i = 0; i < 4; ++i)
                    #pragma unroll
                    for (int j = 0; j < 4; ++j)
                        acc[i][j] += a[i][kk] * wrv[j] + xx[i][kk] * wov[j];
            }
        }
    } else {
        for (int k = 0; k < FIN; ++k) {
            float a[4], xx[4];
            #pragma unroll
            for (int i = 0; i < 4; ++i) {
                int n = n0 + i;
                a[i]  = (n < N_NODES) ? agg[(size_t)n * FIN + k] : 0.f;
                xx[i] = (n < N_NODES) ? x[(size_t)n * FIN + k]   : 0.f;
            }
            float4 wr = *reinterpret_cast<const float4*>(Wrel  + (size_t)k * FOUT + jg * 4);
            float4 wo = *reinterpret_cast<const float4*>(Wroot + (size_t)k * FOUT + jg * 4);
            float wrv[4] = {wr.x, wr.y, wr.z, wr.w};
            float wov[4] = {wo.x, wo.y, wo.z, wo.w};
            #pragma unroll
            for (int i = 0; i < 4; ++i)
                #pragma unroll
                for (int j = 0; j < 4; ++j)
                    acc[i][j] += a[i] * wrv[j] + xx[i] * wov[j];
        }
    }

    float4 b4 = *reinterpret_cast<const float4*>(brel + jg * 4);
    float bv[4] = {b4.x, b4.y, b4.z, b4.w};
    #pragma unroll
    for (int i = 0; i < 4; ++i) {
        int n = n0 + i;
        if (n < N_NODES) {
            #pragma unroll
            for (int j = 0; j < 4; ++j)
                out[(size_t)n * FOUT + jg * 4 + j] = fmaxf(acc[i][j] + bv[j], 0.f);
        }
    }
}

// ===========================================================================
// Dual GEMM (no bias/relu): y = x@Wrel, r = x@Wroot   (for Fout<Fin layers)
// ===========================================================================
template<int FIN, int FOUT>
__global__ void dual_gemm_kernel(const float* __restrict__ x,
                                 const float* __restrict__ Wrel, const float* __restrict__ Wroot,
                                 float* __restrict__ ybuf, float* __restrict__ rbuf) {
    constexpr int JG = FOUT / 4;
    constexpr int NG = 256 / JG;
    constexpr int NT = NG * 4;
    const int tid = threadIdx.x;
    const int jg = tid % JG;
    const int ng = tid / JG;
    const int n0 = blockIdx.x * NT + ng * 4;

    float accy[4][4] = {}, accr[4][4] = {};

    for (int k0 = 0; k0 < FIN; k0 += 4) {
        float xx[4][4];
        #pragma unroll
        for (int i = 0; i < 4; ++i) {
            int n = n0 + i;
            if (n < N_NODES) {
                float4 tx = *reinterpret_cast<const float4*>(x + (size_t)n * FIN + k0);
                xx[i][0] = tx.x; xx[i][1] = tx.y; xx[i][2] = tx.z; xx[i][3] = tx.w;
            } else {
                #pragma unroll
                for (int kk = 0; kk < 4; ++kk) xx[i][kk] = 0.f;
            }
        }
        #pragma unroll
        for (int kk = 0; kk < 4; ++kk) {
            float4 wr = *reinterpret_cast<const float4*>(Wrel  + (size_t)(k0 + kk) * FOUT + jg * 4);
            float4 wo = *reinterpret_cast<const float4*>(Wroot + (size_t)(k0 + kk) * FOUT + jg * 4);
            float wrv[4] = {wr.x, wr.y, wr.z, wr.w};
            float wov[4] = {wo.x, wo.y, wo.z, wo.w};
            #pragma unroll
            for (int i = 0; i < 4; ++i)
                #pragma unroll
                for (int j = 0; j < 4; ++j) {
                    accy[i][j] += xx[i][kk] * wrv[j];
                    accr[i][j] += xx[i][kk] * wov[j];
                }
        }
    }

    #pragma unroll
    for (int i = 0; i < 4; ++i) {
        int n = n0 + i;
        if (n < N_NODES) {
            #pragma unroll
            for (int j = 0; j < 4; ++j) {
                ybuf[(size_t)n * FOUT + jg * 4 + j] = accy[i][j];
                rbuf[(size_t)n * FOUT + jg * 4 + j] = accr[i][j];
            }
        }
    }
}

// ===========================================================================
// Global mean pool + MLP head
// ===========================================================================
__global__ void pool_kernel(const float* __restrict__ x, const int* __restrict__ batch,
                            float* __restrict__ pool, float* __restrict__ cnt) {
    int idx = blockIdx.x * blockDim.x + threadIdx.x;
    if (idx >= N_NODES * 32) return;
    int n = idx >> 5;
    int f = idx & 31;
    int g = batch[n];
    atomicAdd(pool + g * 32 + f, x[(size_t)n * 32 + f]);
    if (f == 0) atomicAdd(cnt + g, 1.0f);
}

__global__ void mlp_kernel(const float* __restrict__ pool, const float* __restrict__ cnt,
                           const float* __restrict__ W0, const float* __restrict__ b0,
                           const float* __restrict__ W1, const float* __restrict__ b1,
                           const float* __restrict__ W2, const float* __restrict__ b2,
                           float* __restrict__ out) {
    int g = blockIdx.x * blockDim.x + threadIdx.x;
    if (g >= NUM_GRAPHS) return;
    float c = fmaxf(cnt[g], 1.0f);
    float h0[32];
    #pragma unroll
    for (int f = 0; f < 32; ++f) h0[f] = pool[g * 32 + f] / c;
    float h1[32];
    for (int j = 0; j < 32; ++j) {
        float s = b0[j];
        for (int k = 0; k < 32; ++k) s += h0[k] * W0[k * 32 + j];
        h1[j] = fmaxf(s, 0.f);
    }
    float h2[16];
    for (int j = 0; j < 16; ++j) {
        float s = b1[j];
        for (int k = 0; k < 32; ++k) s += h1[k] * W1[k * 16 + j];
        h2[j] = fmaxf(s, 0.f);
    }
    float s = b2[0];
    for (int k = 0; k < 16; ++k) s += h2[k] * W2[k];
    out[g] = s;
}

// ===========================================================================
extern "C" void kernel_launch(void* const* d_in, const int* in_sizes, int n_in,
                              void* d_out, int out_size, void* d_ws, size_t ws_size,
                              hipStream_t stream) {
    const float* x_in  = (const float*)d_in[0];
    const int*   ei    = (const int*)d_in[1];
    const int*   src   = ei;
    const int*   dst   = ei + N_EDGES;
    const float* ew    = (const float*)d_in[2];
    const int*   batch = (const int*)d_in[3];

    const float* Wrel[5]  = {(const float*)d_in[4],  (const float*)d_in[7],  (const float*)d_in[10],
                             (const float*)d_in[13], (const float*)d_in[16]};
    const float* brel[5]  = {(const float*)d_in[5],  (const float*)d_in[8],  (const float*)d_in[11],
                             (const float*)d_in[14], (const float*)d_in[17]};
    const float* Wroot[5] = {(const float*)d_in[6],  (const float*)d_in[9],  (const float*)d_in[12],
                             (const float*)d_in[15], (const float*)d_in[18]};
    const float* mW0 = (const float*)d_in[19];
    const float* mb0 = (const float*)d_in[20];
    const float* mW1 = (const float*)d_in[21];
    const float* mb1 = (const float*)d_in[22];
    const float* mW2 = (const float*)d_in[23];
    const float* mb2 = (const float*)d_in[24];

    // workspace layout (floats): A[N*64], B[N*128], C[N*64], CSR, pool
    float* ws = (float*)d_ws;
    float* A = ws;                                 // [N,64]
    float* B = A + (size_t)N_NODES * 64;           // [N,128]
    float* C = B + (size_t)N_NODES * 128;          // [N,64]
    int*   rowptr = (int*)(C + (size_t)N_NODES * 64);   // N+1
    int*   cursor = rowptr + (N_NODES + 2);             // N
    int*   ssrc   = cursor + N_NODES;                   // E
    float* sw     = (float*)(ssrc + N_EDGES);           // E
    float* pool   = sw + N_EDGES;                       // 256*32
    float* cnt    = pool + NUM_GRAPHS * 32;             // 256

    const int BS = 256;
    auto blocks = [](long long total, int bs) { return (int)((total + bs - 1) / bs); };

    // ---- CSR build (once, reused by all 5 layers)
    hipMemsetAsync(cursor, 0, N_NODES * sizeof(int), stream);
    hist_kernel<<<blocks(N_EDGES, BS), BS, 0, stream>>>(dst, cursor);
    scan_kernel<<<1, 1024, 0, stream>>>(cursor, rowptr);
    copy_kernel<<<blocks(N_NODES, BS), BS, 0, stream>>>(rowptr, cursor, N_NODES);
    fill_kernel<<<blocks(N_EDGES, BS), BS, 0, stream>>>(src, dst, ew, cursor, ssrc, sw);

    // ---- Layer 0: 5 -> 32.  gather(x_in)@w5 -> C, GEMM -> B[N,32]
    gather5_kernel<<<blocks(N_NODES, BS), BS, 0, stream>>>(rowptr, ssrc, sw, x_in, C);
    conv_out_kernel<5, 32><<<blocks(N_NODES, 128), BS, 0, stream>>>(C, x_in, Wrel[0], brel[0], Wroot[0], B);

    // ---- Layer 1: 32 -> 64.  gather(B,w32) -> C, GEMM -> A[N,64]
    gather_kernel<32, false><<<blocks(N_NODES, 32), BS, 0, stream>>>(rowptr, ssrc, sw, B, nullptr, nullptr, C);
    conv_out_kernel<32, 64><<<blocks(N_NODES, 64), BS, 0, stream>>>(C, B, Wrel[1], brel[1], Wroot[1], A);

    // ---- Layer 2: 64 -> 128. gather(A,w64) -> C, GEMM -> B[N,128]
    gather_kernel<64, false><<<blocks(N_NODES, 16), BS, 0, stream>>>(rowptr, ssrc, sw, A, nullptr, nullptr, C);
    conv_out_kernel<64, 128><<<blocks(N_NODES, 32), BS, 0, stream>>>(C, A, Wrel[2], brel[2], Wroot[2], B);

    // ---- Layer 3: 128 -> 64. dual GEMM: y=C, r=A; fused gather -> B[N,64]
    dual_gemm_kernel<128, 64><<<blocks(N_NODES, 64), BS, 0, stream>>>(B, Wrel[3], Wroot[3], C, A);
    gather_kernel<64, true><<<blocks(N_NODES, 16), BS, 0, stream>>>(rowptr, ssrc, sw, C, A, brel[3], B);

    // ---- Layer 4: 64 -> 32.  dual GEMM: y=C, r=A; fused gather -> B[N,32]
    dual_gemm_kernel<64, 32><<<blocks(N_NODES, 128), BS, 0, stream>>>(B, Wrel[4], Wroot[4], C, A);
    gather_kernel<32, true><<<blocks(N_NODES, 32), BS, 0, stream>>>(rowptr, ssrc, sw, C, A, brel[4], B);

    // ---- Mean pool + MLP
    hipMemsetAsync(pool, 0, (NUM_GRAPHS * 32 + NUM_GRAPHS) * sizeof(float), stream);
    pool_kernel<<<blocks((long long)N_NODES * 32, BS), BS, 0, stream>>>(B, batch, pool, cnt);
    mlp_kernel<<<1, 256, 0, stream>>>(pool, cnt, mW0, mb0, mW1, mb1, mW2, mb2, (float*)d_out);
}

// Round 3
// 668.096 us; speedup vs baseline: 4.4830x; 1.4498x over previous
//
#include <hip/hip_runtime.h>

#define N_NODES 100000
#define N_EDGES 600000
#define NUM_GRAPHS 256

// ===========================================================================
// CSR build: histogram -> scan -> fill (done once per launch, reused 5x)
// ===========================================================================
__global__ void hist_kernel(const int* __restrict__ dst, int* __restrict__ deg) {
    int e = blockIdx.x * blockDim.x + threadIdx.x;
    if (e < N_EDGES) atomicAdd(&deg[dst[e]], 1);
}

// Single-block exclusive scan of deg[N] -> rowptr[N+1]
__global__ void scan_kernel(const int* __restrict__ deg, int* __restrict__ rowptr) {
    __shared__ int part[1024];
    const int t = threadIdx.x;
    const int CH = (N_NODES + 1023) / 1024;
    int lo = t * CH, hi = min(lo + CH, N_NODES);
    int s = 0;
    for (int i = lo; i < hi; ++i) s += deg[i];
    part[t] = s;
    __syncthreads();
    for (int off = 1; off < 1024; off <<= 1) {
        int v = (t >= off) ? part[t - off] : 0;
        __syncthreads();
        part[t] += v;
        __syncthreads();
    }
    int base = (t == 0) ? 0 : part[t - 1];
    for (int i = lo; i < hi; ++i) { rowptr[i] = base; base += deg[i]; }
    if (t == 1023) rowptr[N_NODES] = part[1023];
}

__global__ void copy_kernel(const int* __restrict__ a, int* __restrict__ b, int n) {
    int i = blockIdx.x * blockDim.x + threadIdx.x;
    if (i < n) b[i] = a[i];
}

__global__ void fill_kernel(const int* __restrict__ src, const int* __restrict__ dst,
                            const float* __restrict__ w, int* __restrict__ cursor,
                            int* __restrict__ ssrc, float* __restrict__ sw) {
    int e = blockIdx.x * blockDim.x + threadIdx.x;
    if (e >= N_EDGES) return;
    int pos = atomicAdd(&cursor[dst[e]], 1);
    ssrc[pos] = src[e];
    sw[pos] = w[e];
}

// ===========================================================================
// CSR gather-aggregate: out[n] = sum_{e in in(n)} y[src_e] * w_e
// F/4 lanes per node, float4 loads, 2x unrolled edge loop.
// FUSED: out = relu(acc + r[n] + b)
// ===========================================================================
template<int F, bool FUSED>
__global__ void gather_kernel(const int* __restrict__ rowptr, const int* __restrict__ ssrc,
                              const float* __restrict__ sw, const float* __restrict__ y,
                              const float* __restrict__ r, const float* __restrict__ b,
                              float* __restrict__ out) {
    constexpr int G = F / 4;
    constexpr int NPB = 256 / G;
    const int tid = threadIdx.x;
    const int c = tid % G;
    const int ln = tid / G;
    const int n = blockIdx.x * NPB + ln;
    if (n >= N_NODES) return;
    const int beg = rowptr[n], end = rowptr[n + 1];
    float4 acc = {0.f, 0.f, 0.f, 0.f};
    int i = beg;
    for (; i + 1 < end; i += 2) {
        int s0 = ssrc[i], s1 = ssrc[i + 1];
        float w0 = sw[i], w1 = sw[i + 1];
        float4 v0 = *(reinterpret_cast<const float4*>(y + (size_t)s0 * F) + c);
        float4 v1 = *(reinterpret_cast<const float4*>(y + (size_t)s1 * F) + c);
        acc.x += v0.x * w0 + v1.x * w1;
        acc.y += v0.y * w0 + v1.y * w1;
        acc.z += v0.z * w0 + v1.z * w1;
        acc.w += v0.w * w0 + v1.w * w1;
    }
    if (i < end) {
        int s0 = ssrc[i];
        float w0 = sw[i];
        float4 v0 = *(reinterpret_cast<const float4*>(y + (size_t)s0 * F) + c);
        acc.x += v0.x * w0; acc.y += v0.y * w0; acc.z += v0.z * w0; acc.w += v0.w * w0;
    }
    if constexpr (FUSED) {
        float4 rv = *(reinterpret_cast<const float4*>(r + (size_t)n * F) + c);
        float4 bv = *(reinterpret_cast<const float4*>(b) + c);
        acc.x = fmaxf(acc.x + rv.x + bv.x, 0.f);
        acc.y = fmaxf(acc.y + rv.y + bv.y, 0.f);
        acc.z = fmaxf(acc.z + rv.z + bv.z, 0.f);
        acc.w = fmaxf(acc.w + rv.w + bv.w, 0.f);
    }
    *(reinterpret_cast<float4*>(out + (size_t)n * F) + c) = acc;
}

// width-5 input layer: one thread per node
__global__ void gather5_kernel(const int* __restrict__ rowptr, const int* __restrict__ ssrc,
                               const float* __restrict__ sw, const float* __restrict__ x,
                               float* __restrict__ agg) {
    int n = blockIdx.x * blockDim.x + threadIdx.x;
    if (n >= N_NODES) return;
    float a0 = 0.f, a1 = 0.f, a2 = 0.f, a3 = 0.f, a4 = 0.f;
    for (int i = rowptr[n]; i < rowptr[n + 1]; ++i) {
        int s = ssrc[i];
        float we = sw[i];
        const float* xs = x + (size_t)s * 5;
        a0 += xs[0] * we; a1 += xs[1] * we; a2 += xs[2] * we;
        a3 += xs[3] * we; a4 += xs[4] * we;
    }
    float* o = agg + (size_t)n * 5;
    o[0] = a0; o[1] = a1; o[2] = a2; o[3] = a3; o[4] = a4;
}

// ===========================================================================
// out[n][j] = relu( agg[n]@Wrel + brel + x[n]@Wroot )  -- 4 nodes x 4 outs/thread
// ===========================================================================
template<int FIN, int FOUT>
__global__ void conv_out_kernel(const float* __restrict__ agg, const float* __restrict__ x,
                                const float* __restrict__ Wrel, const float* __restrict__ brel,
                                const float* __restrict__ Wroot, float* __restrict__ out) {
    constexpr int JG = FOUT / 4;
    constexpr int NG = 256 / JG;
    constexpr int NT = NG * 4;
    const int tid = threadIdx.x;
    const int jg = tid % JG;
    const int ng = tid / JG;
    const int n0 = blockIdx.x * NT + ng * 4;

    float acc[4][4] = {};

    if constexpr (FIN % 4 == 0) {
        for (int k0 = 0; k0 < FIN; k0 += 4) {
            float a[4][4], xx[4][4];
            #pragma unroll
            for (int i = 0; i < 4; ++i) {
                int n = n0 + i;
                if (n < N_NODES) {
                    float4 ta = *reinterpret_cast<const float4*>(agg + (size_t)n * FIN + k0);
                    float4 tx = *reinterpret_cast<const float4*>(x   + (size_t)n * FIN + k0);
                    a[i][0] = ta.x; a[i][1] = ta.y; a[i][2] = ta.z; a[i][3] = ta.w;
                    xx[i][0] = tx.x; xx[i][1] = tx.y; xx[i][2] = tx.z; xx[i][3] = tx.w;
                } else {
                    #pragma unroll
                    for (int kk = 0; kk < 4; ++kk) { a[i][kk] = 0.f; xx[i][kk] = 0.f; }
                }
            }
            #pragma unroll
            for (int kk = 0; kk < 4; ++kk) {
                float4 wr = *reinterpret_cast<const float4*>(Wrel  + (size_t)(k0 + kk) * FOUT + jg * 4);
                float4 wo = *reinterpret_cast<const float4*>(Wroot + (size_t)(k0 + kk) * FOUT + jg * 4);
                float wrv[4] = {wr.x, wr.y, wr.z, wr.w};
                float wov[4] = {wo.x, wo.y, wo.z, wo.w};
                #pragma unroll
                for (int i = 0; i < 4; ++i)
                    #pragma unroll
                    for (int j = 0; j < 4; ++j)
                        acc[i][j] += a[i][kk] * wrv[j] + xx[i][kk] * wov[j];
            }
        }
    } else {
        for (int k = 0; k < FIN; ++k) {
            float a[4], xx[4];
            #pragma unroll
            for (int i = 0; i < 4; ++i) {
                int n = n0 + i;
                a[i]  = (n < N_NODES) ? agg[(size_t)n * FIN + k] : 0.f;
                xx[i] = (n < N_NODES) ? x[(size_t)n * FIN + k]   : 0.f;
            }
            float4 wr = *reinterpret_cast<const float4*>(Wrel  + (size_t)k * FOUT + jg * 4);
            float4 wo = *reinterpret_cast<const float4*>(Wroot + (size_t)k * FOUT + jg * 4);
            float wrv[4] = {wr.x, wr.y, wr.z, wr.w};
            float wov[4] = {wo.x, wo.y, wo.z, wo.w};
            #pragma unroll
            for (int i = 0; i < 4; ++i)
                #pragma unroll
                for (int j = 0; j < 4; ++j)
                    acc[i][j] += a[i] * wrv[j] + xx[i] * wov[j];
        }
    }

    float4 b4 = *reinterpret_cast<const float4*>(brel + jg * 4);
    float bv[4] = {b4.x, b4.y, b4.z, b4.w};
    #pragma unroll
    for (int i = 0; i < 4; ++i) {
        int n = n0 + i;
        if (n < N_NODES) {
            #pragma unroll
            for (int j = 0; j < 4; ++j)
                out[(size_t)n * FOUT + jg * 4 + j] = fmaxf(acc[i][j] + bv[j], 0.f);
        }
    }
}

// ===========================================================================
// Dual GEMM (no bias/relu): y = x@Wrel, r = x@Wroot   (for Fout<Fin layers)
// ===========================================================================
template<int FIN, int FOUT>
__global__ void dual_gemm_kernel(const float* __restrict__ x,
                                 const float* __restrict__ Wrel, const float* __restrict__ Wroot,
                                 float* __restrict__ ybuf, float* __restrict__ rbuf) {
    constexpr int JG = FOUT / 4;
    constexpr int NG = 256 / JG;
    constexpr int NT = NG * 4;
    const int tid = threadIdx.x;
    const int jg = tid % JG;
    const int ng = tid / JG;
    const int n0 = blockIdx.x * NT + ng * 4;

    float accy[4][4] = {}, accr[4][4] = {};

    for (int k0 = 0; k0 < FIN; k0 += 4) {
        float xx[4][4];
        #pragma unroll
        for (int i = 0; i < 4; ++i) {
            int n = n0 + i;
            if (n < N_NODES) {
                float4 tx = *reinterpret_cast<const float4*>(x + (size_t)n * FIN + k0);
                xx[i][0] = tx.x; xx[i][1] = tx.y; xx[i][2] = tx.z; xx[i][3] = tx.w;
            } else {
                #pragma unroll
                for (int kk = 0; kk < 4; ++kk) xx[i][kk] = 0.f;
            }
        }
        #pragma unroll
        for (int kk = 0; kk < 4; ++kk) {
            float4 wr = *reinterpret_cast<const float4*>(Wrel  + (size_t)(k0 + kk) * FOUT + jg * 4);
            float4 wo = *reinterpret_cast<const float4*>(Wroot + (size_t)(k0 + kk) * FOUT + jg * 4);
            float wrv[4] = {wr.x, wr.y, wr.z, wr.w};
            float wov[4] = {wo.x, wo.y, wo.z, wo.w};
            #pragma unroll
            for (int i = 0; i < 4; ++i)
                #pragma unroll
                for (int j = 0; j < 4; ++j) {
                    accy[i][j] += xx[i][kk] * wrv[j];
                    accr[i][j] += xx[i][kk] * wov[j];
                }
        }
    }

    #pragma unroll
    for (int i = 0; i < 4; ++i) {
        int n = n0 + i;
        if (n < N_NODES) {
            #pragma unroll
            for (int j = 0; j < 4; ++j) {
                ybuf[(size_t)n * FOUT + jg * 4 + j] = accy[i][j];
                rbuf[(size_t)n * FOUT + jg * 4 + j] = accr[i][j];
            }
        }
    }
}

// ===========================================================================
// Fused mean-pool + MLP head. batch[] is SORTED -> graph g owns a contiguous
// node range found by binary search. One block per graph, zero atomics.
// ===========================================================================
__global__ void pool_mlp_kernel(const float* __restrict__ x, const int* __restrict__ batch,
                                const float* __restrict__ W0, const float* __restrict__ b0,
                                const float* __restrict__ W1, const float* __restrict__ b1,
                                const float* __restrict__ W2, const float* __restrict__ b2,
                                float* __restrict__ out) {
    const int g = blockIdx.x;
    // lower_bound(batch, key): first index with batch[i] >= key
    auto lb = [&](int key) {
        int lo = 0, hi = N_NODES;
        while (lo < hi) {
            int mid = (lo + hi) >> 1;
            if (batch[mid] < key) lo = mid + 1; else hi = mid;
        }
        return lo;
    };
    const int beg = lb(g), end = lb(g + 1);

    const int t = threadIdx.x;     // 256 threads
    const int q = t & 7;           // float4 lane (8 quads = 32 feats)
    const int r = t >> 3;          // 32 node-lanes

    float4 s = {0.f, 0.f, 0.f, 0.f};
    for (int n = beg + r; n < end; n += 32) {
        float4 v = *(reinterpret_cast<const float4*>(x + (size_t)n * 32) + q);
        s.x += v.x; s.y += v.y; s.z += v.z; s.w += v.w;
    }
    __shared__ float4 red[32][8];
    red[r][q] = s;
    __syncthreads();

    __shared__ float h0[32], h1[32], h2[16];
    if (r == 0) {   // 8 threads, one per quad
        float4 tot = {0.f, 0.f, 0.f, 0.f};
        #pragma unroll
        for (int i = 0; i < 32; ++i) {
            float4 v = red[i][q];
            tot.x += v.x; tot.y += v.y; tot.z += v.z; tot.w += v.w;
        }
        float c = fmaxf((float)(end - beg), 1.0f);
        h0[q * 4 + 0] = tot.x / c;
        h0[q * 4 + 1] = tot.y / c;
        h0[q * 4 + 2] = tot.z / c;
        h0[q * 4 + 3] = tot.w / c;
    }
    __syncthreads();
    if (t < 32) {
        float s1 = b0[t];
        for (int k = 0; k < 32; ++k) s1 += h0[k] * W0[k * 32 + t];
        h1[t] = fmaxf(s1, 0.f);
    }
    __syncthreads();
    if (t < 16) {
        float s2 = b1[t];
        for (int k = 0; k < 32; ++k) s2 += h1[k] * W1[k * 16 + t];
        h2[t] = fmaxf(s2, 0.f);
    }
    __syncthreads();
    if (t == 0) {
        float s3 = b2[0];
        for (int k = 0; k < 16; ++k) s3 += h2[k] * W2[k];
        out[g] = s3;
    }
}

// ===========================================================================
extern "C" void kernel_launch(void* const* d_in, const int* in_sizes, int n_in,
                              void* d_out, int out_size, void* d_ws, size_t ws_size,
                              hipStream_t stream) {
    const float* x_in  = (const float*)d_in[0];
    const int*   ei    = (const int*)d_in[1];
    const int*   src   = ei;
    const int*   dst   = ei + N_EDGES;
    const float* ew    = (const float*)d_in[2];
    const int*   batch = (const int*)d_in[3];

    const float* Wrel[5]  = {(const float*)d_in[4],  (const float*)d_in[7],  (const float*)d_in[10],
                             (const float*)d_in[13], (const float*)d_in[16]};
    const float* brel[5]  = {(const float*)d_in[5],  (const float*)d_in[8],  (const float*)d_in[11],
                             (const float*)d_in[14], (const float*)d_in[17]};
    const float* Wroot[5] = {(const float*)d_in[6],  (const float*)d_in[9],  (const float*)d_in[12],
                             (const float*)d_in[15], (const float*)d_in[18]};
    const float* mW0 = (const float*)d_in[19];
    const float* mb0 = (const float*)d_in[20];
    const float* mW1 = (const float*)d_in[21];
    const float* mb1 = (const float*)d_in[22];
    const float* mW2 = (const float*)d_in[23];
    const float* mb2 = (const float*)d_in[24];

    // workspace layout (floats): A[N*64], B[N*128], C[N*64], CSR
    float* ws = (float*)d_ws;
    float* A = ws;                                 // [N,64]
    float* B = A + (size_t)N_NODES * 64;           // [N,128]
    float* C = B + (size_t)N_NODES * 128;          // [N,64]
    int*   rowptr = (int*)(C + (size_t)N_NODES * 64);   // N+1
    int*   cursor = rowptr + (N_NODES + 2);             // N
    int*   ssrc   = cursor + N_NODES;                   // E
    float* sw     = (float*)(ssrc + N_EDGES);           // E

    const int BS = 256;
    auto blocks = [](long long total, int bs) { return (int)((total + bs - 1) / bs); };

    // ---- CSR build (once, reused by all 5 layers)
    hipMemsetAsync(cursor, 0, N_NODES * sizeof(int), stream);
    hist_kernel<<<blocks(N_EDGES, BS), BS, 0, stream>>>(dst, cursor);
    scan_kernel<<<1, 1024, 0, stream>>>(cursor, rowptr);
    copy_kernel<<<blocks(N_NODES, BS), BS, 0, stream>>>(rowptr, cursor, N_NODES);
    fill_kernel<<<blocks(N_EDGES, BS), BS, 0, stream>>>(src, dst, ew, cursor, ssrc, sw);

    // ---- Layer 0: 5 -> 32.  gather(x_in)@w5 -> C, GEMM -> B[N,32]
    gather5_kernel<<<blocks(N_NODES, BS), BS, 0, stream>>>(rowptr, ssrc, sw, x_in, C);
    conv_out_kernel<5, 32><<<blocks(N_NODES, 128), BS, 0, stream>>>(C, x_in, Wrel[0], brel[0], Wroot[0], B);

    // ---- Layer 1: 32 -> 64.  gather(B,w32) -> C, GEMM -> A[N,64]
    gather_kernel<32, false><<<blocks(N_NODES, 32), BS, 0, stream>>>(rowptr, ssrc, sw, B, nullptr, nullptr, C);
    conv_out_kernel<32, 64><<<blocks(N_NODES, 64), BS, 0, stream>>>(C, B, Wrel[1], brel[1], Wroot[1], A);

    // ---- Layer 2: 64 -> 128. gather(A,w64) -> C, GEMM -> B[N,128]
    gather_kernel<64, false><<<blocks(N_NODES, 16), BS, 0, stream>>>(rowptr, ssrc, sw, A, nullptr, nullptr, C);
    conv_out_kernel<64, 128><<<blocks(N_NODES, 32), BS, 0, stream>>>(C, A, Wrel[2], brel[2], Wroot[2], B);

    // ---- Layer 3: 128 -> 64. dual GEMM: y=C, r=A; fused gather -> B[N,64]
    dual_gemm_kernel<128, 64><<<blocks(N_NODES, 64), BS, 0, stream>>>(B, Wrel[3], Wroot[3], C, A);
    gather_kernel<64, true><<<blocks(N_NODES, 16), BS, 0, stream>>>(rowptr, ssrc, sw, C, A, brel[3], B);

    // ---- Layer 4: 64 -> 32.  dual GEMM: y=C, r=A; fused gather -> B[N,32]
    dual_gemm_kernel<64, 32><<<blocks(N_NODES, 128), BS, 0, stream>>>(B, Wrel[4], Wroot[4], C, A);
    gather_kernel<32, true><<<blocks(N_NODES, 32), BS, 0, stream>>>(rowptr, ssrc, sw, C, A, brel[4], B);

    // ---- Fused mean pool + MLP (batch sorted -> per-graph contiguous ranges)
    pool_mlp_kernel<<<NUM_GRAPHS, 256, 0, stream>>>(B, batch, mW0, mb0, mW1, mb1, mW2, mb2, (float*)d_out);
}

// Round 4
// 512.705 us; speedup vs baseline: 5.8418x; 1.3031x over previous
//
#include <hip/hip_runtime.h>

#define N_NODES 100000
#define N_EDGES 600000
#define NUM_GRAPHS 256

#define SCAN_BS   256
#define SCAN_CH   4
#define SCAN_CHUNK (SCAN_BS * SCAN_CH)                      // 1024
#define SCAN_NB   ((N_NODES + SCAN_CHUNK - 1) / SCAN_CHUNK) // 98

// ===========================================================================
// CSR build: histogram -> 3-phase scan -> fill (once per launch, reused 5x)
// ===========================================================================
__global__ void hist_kernel(const int* __restrict__ dst, int* __restrict__ deg) {
    int e = blockIdx.x * blockDim.x + threadIdx.x;
    if (e < N_EDGES) atomicAdd(&deg[dst[e]], 1);
}

// Phase 1: per-block partial sums of deg
__global__ void scan_p1_kernel(const int* __restrict__ deg, int* __restrict__ bsum) {
    __shared__ int sh[SCAN_BS];
    const int b = blockIdx.x, t = threadIdx.x;
    const int base = b * SCAN_CHUNK + t * SCAN_CH;
    int s = 0;
    #pragma unroll
    for (int k = 0; k < SCAN_CH; ++k) {
        int i = base + k;
        if (i < N_NODES) s += deg[i];
    }
    sh[t] = s;
    __syncthreads();
    for (int off = SCAN_BS / 2; off > 0; off >>= 1) {
        if (t < off) sh[t] += sh[t + off];
        __syncthreads();
    }
    if (t == 0) bsum[b] = sh[0];
}

// Phase 2: exclusive scan of the 98 block sums (single tiny block)
__global__ void scan_p2_kernel(int* __restrict__ bsum, int* __restrict__ rowptr) {
    __shared__ int sh[128];
    const int t = threadIdx.x;
    int v = (t < SCAN_NB) ? bsum[t] : 0;
    sh[t] = v;
    __syncthreads();
    for (int off = 1; off < 128; off <<= 1) {
        int u = (t >= off) ? sh[t - off] : 0;
        __syncthreads();
        sh[t] += u;
        __syncthreads();
    }
    if (t < SCAN_NB) bsum[t] = sh[t] - v;   // exclusive block offset
    if (t == 0) rowptr[N_NODES] = N_EDGES;  // total is a known constant
}

// Phase 3: per-chunk scan + write rowptr AND cursor (replaces copy_kernel)
__global__ void scan_p3_kernel(const int* __restrict__ deg, const int* __restrict__ bsum,
                               int* __restrict__ rowptr, int* __restrict__ cursor) {
    __shared__ int sh[SCAN_BS];
    const int b = blockIdx.x, t = threadIdx.x;
    const int base = b * SCAN_CHUNK + t * SCAN_CH;
    int v[SCAN_CH];
    int s = 0;
    #pragma unroll
    for (int k = 0; k < SCAN_CH; ++k) {
        int i = base + k;
        v[k] = (i < N_NODES) ? deg[i] : 0;
        s += v[k];
    }
    sh[t] = s;
    __syncthreads();
    for (int off = 1; off < SCAN_BS; off <<= 1) {
        int u = (t >= off) ? sh[t - off] : 0;
        __syncthreads();
        sh[t] += u;
        __syncthreads();
    }
    int run = bsum[b] + sh[t] - s;   // exclusive prefix for this thread's chunk
    #pragma unroll
    for (int k = 0; k < SCAN_CH; ++k) {
        int i = base + k;
        if (i < N_NODES) { rowptr[i] = run; cursor[i] = run; }
        run += v[k];
    }
}

__global__ void fill_kernel(const int* __restrict__ src, const int* __restrict__ dst,
                            const float* __restrict__ w, int* __restrict__ cursor,
                            int* __restrict__ ssrc, float* __restrict__ sw) {
    int e = blockIdx.x * blockDim.x + threadIdx.x;
    if (e >= N_EDGES) return;
    int pos = atomicAdd(&cursor[dst[e]], 1);
    ssrc[pos] = src[e];
    sw[pos] = w[e];
}

// ===========================================================================
// CSR gather-aggregate: out[n] = sum_{e in in(n)} y[src_e] * w_e
// F/4 lanes per node, float4 loads, 2x unrolled edge loop.
// FUSED: out = relu(acc + r[n] + b)
// ===========================================================================
template<int F, bool FUSED>
__global__ void gather_kernel(const int* __restrict__ rowptr, const int* __restrict__ ssrc,
                              const float* __restrict__ sw, const float* __restrict__ y,
                              const float* __restrict__ r, const float* __restrict__ b,
                              float* __restrict__ out) {
    constexpr int G = F / 4;
    constexpr int NPB = 256 / G;
    const int tid = threadIdx.x;
    const int c = tid % G;
    const int ln = tid / G;
    const int n = blockIdx.x * NPB + ln;
    if (n >= N_NODES) return;
    const int beg = rowptr[n], end = rowptr[n + 1];
    float4 acc = {0.f, 0.f, 0.f, 0.f};
    int i = beg;
    for (; i + 1 < end; i += 2) {
        int s0 = ssrc[i], s1 = ssrc[i + 1];
        float w0 = sw[i], w1 = sw[i + 1];
        float4 v0 = *(reinterpret_cast<const float4*>(y + (size_t)s0 * F) + c);
        float4 v1 = *(reinterpret_cast<const float4*>(y + (size_t)s1 * F) + c);
        acc.x += v0.x * w0 + v1.x * w1;
        acc.y += v0.y * w0 + v1.y * w1;
        acc.z += v0.z * w0 + v1.z * w1;
        acc.w += v0.w * w0 + v1.w * w1;
    }
    if (i < end) {
        int s0 = ssrc[i];
        float w0 = sw[i];
        float4 v0 = *(reinterpret_cast<const float4*>(y + (size_t)s0 * F) + c);
        acc.x += v0.x * w0; acc.y += v0.y * w0; acc.z += v0.z * w0; acc.w += v0.w * w0;
    }
    if constexpr (FUSED) {
        float4 rv = *(reinterpret_cast<const float4*>(r + (size_t)n * F) + c);
        float4 bv = *(reinterpret_cast<const float4*>(b) + c);
        acc.x = fmaxf(acc.x + rv.x + bv.x, 0.f);
        acc.y = fmaxf(acc.y + rv.y + bv.y, 0.f);
        acc.z = fmaxf(acc.z + rv.z + bv.z, 0.f);
        acc.w = fmaxf(acc.w + rv.w + bv.w, 0.f);
    }
    *(reinterpret_cast<float4*>(out + (size_t)n * F) + c) = acc;
}

// width-5 input layer: one thread per node
__global__ void gather5_kernel(const int* __restrict__ rowptr, const int* __restrict__ ssrc,
                               const float* __restrict__ sw, const float* __restrict__ x,
                               float* __restrict__ agg) {
    int n = blockIdx.x * blockDim.x + threadIdx.x;
    if (n >= N_NODES) return;
    float a0 = 0.f, a1 = 0.f, a2 = 0.f, a3 = 0.f, a4 = 0.f;
    for (int i = rowptr[n]; i < rowptr[n + 1]; ++i) {
        int s = ssrc[i];
        float we = sw[i];
        const float* xs = x + (size_t)s * 5;
        a0 += xs[0] * we; a1 += xs[1] * we; a2 += xs[2] * we;
        a3 += xs[3] * we; a4 += xs[4] * we;
    }
    float* o = agg + (size_t)n * 5;
    o[0] = a0; o[1] = a1; o[2] = a2; o[3] = a3; o[4] = a4;
}

// ===========================================================================
// out[n][j] = relu( agg[n]@Wrel + brel + x[n]@Wroot )  -- 4 nodes x 4 outs/thread
// ===========================================================================
template<int FIN, int FOUT>
__global__ void conv_out_kernel(const float* __restrict__ agg, const float* __restrict__ x,
                                const float* __restrict__ Wrel, const float* __restrict__ brel,
                                const float* __restrict__ Wroot, float* __restrict__ out) {
    constexpr int JG = FOUT / 4;
    constexpr int NG = 256 / JG;
    constexpr int NT = NG * 4;
    const int tid = threadIdx.x;
    const int jg = tid % JG;
    const int ng = tid / JG;
    const int n0 = blockIdx.x * NT + ng * 4;

    float acc[4][4] = {};

    if constexpr (FIN % 4 == 0) {
        for (int k0 = 0; k0 < FIN; k0 += 4) {
            float a[4][4], xx[4][4];
            #pragma unroll
            for (int i = 0; i < 4; ++i) {
                int n = n0 + i;
                if (n < N_NODES) {
                    float4 ta = *reinterpret_cast<const float4*>(agg + (size_t)n * FIN + k0);
                    float4 tx = *reinterpret_cast<const float4*>(x   + (size_t)n * FIN + k0);
                    a[i][0] = ta.x; a[i][1] = ta.y; a[i][2] = ta.z; a[i][3] = ta.w;
                    xx[i][0] = tx.x; xx[i][1] = tx.y; xx[i][2] = tx.z; xx[i][3] = tx.w;
                } else {
                    #pragma unroll
                    for (int kk = 0; kk < 4; ++kk) { a[i][kk] = 0.f; xx[i][kk] = 0.f; }
                }
            }
            #pragma unroll
            for (int kk = 0; kk < 4; ++kk) {
                float4 wr = *reinterpret_cast<const float4*>(Wrel  + (size_t)(k0 + kk) * FOUT + jg * 4);
                float4 wo = *reinterpret_cast<const float4*>(Wroot + (size_t)(k0 + kk) * FOUT + jg * 4);
                float wrv[4] = {wr.x, wr.y, wr.z, wr.w};
                float wov[4] = {wo.x, wo.y, wo.z, wo.w};
                #pragma unroll
                for (int i = 0; i < 4; ++i)
                    #pragma unroll
                    for (int j = 0; j < 4; ++j)
                        acc[i][j] += a[i][kk] * wrv[j] + xx[i][kk] * wov[j];
            }
        }
    } else {
        for (int k = 0; k < FIN; ++k) {
            float a[4], xx[4];
            #pragma unroll
            for (int i = 0; i < 4; ++i) {
                int n = n0 + i;
                a[i]  = (n < N_NODES) ? agg[(size_t)n * FIN + k] : 0.f;
                xx[i] = (n < N_NODES) ? x[(size_t)n * FIN + k]   : 0.f;
            }
            float4 wr = *reinterpret_cast<const float4*>(Wrel  + (size_t)k * FOUT + jg * 4);
            float4 wo = *reinterpret_cast<const float4*>(Wroot + (size_t)k * FOUT + jg * 4);
            float wrv[4] = {wr.x, wr.y, wr.z, wr.w};
            float wov[4] = {wo.x, wo.y, wo.z, wo.w};
            #pragma unroll
            for (int i = 0; i < 4; ++i)
                #pragma unroll
                for (int j = 0; j < 4; ++j)
                    acc[i][j] += a[i] * wrv[j] + xx[i] * wov[j];
        }
    }

    float4 b4 = *reinterpret_cast<const float4*>(brel + jg * 4);
    float bv[4] = {b4.x, b4.y, b4.z, b4.w};
    #pragma unroll
    for (int i = 0; i < 4; ++i) {
        int n = n0 + i;
        if (n < N_NODES) {
            #pragma unroll
            for (int j = 0; j < 4; ++j)
                out[(size_t)n * FOUT + jg * 4 + j] = fmaxf(acc[i][j] + bv[j], 0.f);
        }
    }
}

// ===========================================================================
// Dual GEMM (no bias/relu): y = x@Wrel, r = x@Wroot   (for Fout<Fin layers)
// ===========================================================================
template<int FIN, int FOUT>
__global__ void dual_gemm_kernel(const float* __restrict__ x,
                                 const float* __restrict__ Wrel, const float* __restrict__ Wroot,
                                 float* __restrict__ ybuf, float* __restrict__ rbuf) {
    constexpr int JG = FOUT / 4;
    constexpr int NG = 256 / JG;
    constexpr int NT = NG * 4;
    const int tid = threadIdx.x;
    const int jg = tid % JG;
    const int ng = tid / JG;
    const int n0 = blockIdx.x * NT + ng * 4;

    float accy[4][4] = {}, accr[4][4] = {};

    for (int k0 = 0; k0 < FIN; k0 += 4) {
        float xx[4][4];
        #pragma unroll
        for (int i = 0; i < 4; ++i) {
            int n = n0 + i;
            if (n < N_NODES) {
                float4 tx = *reinterpret_cast<const float4*>(x + (size_t)n * FIN + k0);
                xx[i][0] = tx.x; xx[i][1] = tx.y; xx[i][2] = tx.z; xx[i][3] = tx.w;
            } else {
                #pragma unroll
                for (int kk = 0; kk < 4; ++kk) xx[i][kk] = 0.f;
            }
        }
        #pragma unroll
        for (int kk = 0; kk < 4; ++kk) {
            float4 wr = *reinterpret_cast<const float4*>(Wrel  + (size_t)(k0 + kk) * FOUT + jg * 4);
            float4 wo = *reinterpret_cast<const float4*>(Wroot + (size_t)(k0 + kk) * FOUT + jg * 4);
            float wrv[4] = {wr.x, wr.y, wr.z, wr.w};
            float wov[4] = {wo.x, wo.y, wo.z, wo.w};
            #pragma unroll
            for (int i = 0; i < 4; ++i)
                #pragma unroll
                for (int j = 0; j < 4; ++j) {
                    accy[i][j] += xx[i][kk] * wrv[j];
                    accr[i][j] += xx[i][kk] * wov[j];
                }
        }
    }

    #pragma unroll
    for (int i = 0; i < 4; ++i) {
        int n = n0 + i;
        if (n < N_NODES) {
            #pragma unroll
            for (int j = 0; j < 4; ++j) {
                ybuf[(size_t)n * FOUT + jg * 4 + j] = accy[i][j];
                rbuf[(size_t)n * FOUT + jg * 4 + j] = accr[i][j];
            }
        }
    }
}

// ===========================================================================
// Fused mean-pool + MLP head. batch[] is SORTED -> per-graph contiguous range.
// One block per graph, zero atomics.
// ===========================================================================
__global__ void pool_mlp_kernel(const float* __restrict__ x, const int* __restrict__ batch,
                                const float* __restrict__ W0, const float* __restrict__ b0,
                                const float* __restrict__ W1, const float* __restrict__ b1,
                                const float* __restrict__ W2, const float* __restrict__ b2,
                                float* __restrict__ out) {
    const int g = blockIdx.x;
    auto lb = [&](int key) {
        int lo = 0, hi = N_NODES;
        while (lo < hi) {
            int mid = (lo + hi) >> 1;
            if (batch[mid] < key) lo = mid + 1; else hi = mid;
        }
        return lo;
    };
    const int beg = lb(g), end = lb(g + 1);

    const int t = threadIdx.x;
    const int q = t & 7;
    const int r = t >> 3;

    float4 s = {0.f, 0.f, 0.f, 0.f};
    for (int n = beg + r; n < end; n += 32) {
        float4 v = *(reinterpret_cast<const float4*>(x + (size_t)n * 32) + q);
        s.x += v.x; s.y += v.y; s.z += v.z; s.w += v.w;
    }
    __shared__ float4 red[32][8];
    red[r][q] = s;
    __syncthreads();

    __shared__ float h0[32], h1[32], h2[16];
    if (r == 0) {
        float4 tot = {0.f, 0.f, 0.f, 0.f};
        #pragma unroll
        for (int i = 0; i < 32; ++i) {
            float4 v = red[i][q];
            tot.x += v.x; tot.y += v.y; tot.z += v.z; tot.w += v.w;
        }
        float c = fmaxf((float)(end - beg), 1.0f);
        h0[q * 4 + 0] = tot.x / c;
        h0[q * 4 + 1] = tot.y / c;
        h0[q * 4 + 2] = tot.z / c;
        h0[q * 4 + 3] = tot.w / c;
    }
    __syncthreads();
    if (t < 32) {
        float s1 = b0[t];
        for (int k = 0; k < 32; ++k) s1 += h0[k] * W0[k * 32 + t];
        h1[t] = fmaxf(s1, 0.f);
    }
    __syncthreads();
    if (t < 16) {
        float s2 = b1[t];
        for (int k = 0; k < 32; ++k) s2 += h1[k] * W1[k * 16 + t];
        h2[t] = fmaxf(s2, 0.f);
    }
    __syncthreads();
    if (t == 0) {
        float s3 = b2[0];
        for (int k = 0; k < 16; ++k) s3 += h2[k] * W2[k];
        out[g] = s3;
    }
}

// ===========================================================================
extern "C" void kernel_launch(void* const* d_in, const int* in_sizes, int n_in,
                              void* d_out, int out_size, void* d_ws, size_t ws_size,
                              hipStream_t stream) {
    const float* x_in  = (const float*)d_in[0];
    const int*   ei    = (const int*)d_in[1];
    const int*   src   = ei;
    const int*   dst   = ei + N_EDGES;
    const float* ew    = (const float*)d_in[2];
    const int*   batch = (const int*)d_in[3];

    const float* Wrel[5]  = {(const float*)d_in[4],  (const float*)d_in[7],  (const float*)d_in[10],
                             (const float*)d_in[13], (const float*)d_in[16]};
    const float* brel[5]  = {(const float*)d_in[5],  (const float*)d_in[8],  (const float*)d_in[11],
                             (const float*)d_in[14], (const float*)d_in[17]};
    const float* Wroot[5] = {(const float*)d_in[6],  (const float*)d_in[9],  (const float*)d_in[12],
                             (const float*)d_in[15], (const float*)d_in[18]};
    const float* mW0 = (const float*)d_in[19];
    const float* mb0 = (const float*)d_in[20];
    const float* mW1 = (const float*)d_in[21];
    const float* mb1 = (const float*)d_in[22];
    const float* mW2 = (const float*)d_in[23];
    const float* mb2 = (const float*)d_in[24];

    // workspace layout (floats): A[N*64], B[N*128], C[N*64], CSR
    float* ws = (float*)d_ws;
    float* A = ws;                                 // [N,64]
    float* B = A + (size_t)N_NODES * 64;           // [N,128]
    float* C = B + (size_t)N_NODES * 128;          // [N,64]
    int*   rowptr = (int*)(C + (size_t)N_NODES * 64);   // N+1
    int*   cursor = rowptr + (N_NODES + 2);             // N
    int*   deg    = cursor + N_NODES;                   // N
    int*   bsum   = deg + N_NODES;                      // SCAN_NB
    int*   ssrc   = bsum + 128;                         // E
    float* sw     = (float*)(ssrc + N_EDGES);           // E

    const int BS = 256;
    auto blocks = [](long long total, int bs) { return (int)((total + bs - 1) / bs); };

    // ---- CSR build (once, reused by all 5 layers)
    hipMemsetAsync(deg, 0, N_NODES * sizeof(int), stream);
    hist_kernel<<<blocks(N_EDGES, BS), BS, 0, stream>>>(dst, deg);
    scan_p1_kernel<<<SCAN_NB, SCAN_BS, 0, stream>>>(deg, bsum);
    scan_p2_kernel<<<1, 128, 0, stream>>>(bsum, rowptr);
    scan_p3_kernel<<<SCAN_NB, SCAN_BS, 0, stream>>>(deg, bsum, rowptr, cursor);
    fill_kernel<<<blocks(N_EDGES, BS), BS, 0, stream>>>(src, dst, ew, cursor, ssrc, sw);

    // ---- Layer 0: 5 -> 32.  gather(x_in)@w5 -> C, GEMM -> B[N,32]
    gather5_kernel<<<blocks(N_NODES, BS), BS, 0, stream>>>(rowptr, ssrc, sw, x_in, C);
    conv_out_kernel<5, 32><<<blocks(N_NODES, 128), BS, 0, stream>>>(C, x_in, Wrel[0], brel[0], Wroot[0], B);

    // ---- Layer 1: 32 -> 64.  gather(B,w32) -> C, GEMM -> A[N,64]
    gather_kernel<32, false><<<blocks(N_NODES, 32), BS, 0, stream>>>(rowptr, ssrc, sw, B, nullptr, nullptr, C);
    conv_out_kernel<32, 64><<<blocks(N_NODES, 64), BS, 0, stream>>>(C, B, Wrel[1], brel[1], Wroot[1], A);

    // ---- Layer 2: 64 -> 128. gather(A,w64) -> C, GEMM -> B[N,128]
    gather_kernel<64, false><<<blocks(N_NODES, 16), BS, 0, stream>>>(rowptr, ssrc, sw, A, nullptr, nullptr, C);
    conv_out_kernel<64, 128><<<blocks(N_NODES, 32), BS, 0, stream>>>(C, A, Wrel[2], brel[2], Wroot[2], B);

    // ---- Layer 3: 128 -> 64. dual GEMM: y=C, r=A; fused gather -> B[N,64]
    dual_gemm_kernel<128, 64><<<blocks(N_NODES, 64), BS, 0, stream>>>(B, Wrel[3], Wroot[3], C, A);
    gather_kernel<64, true><<<blocks(N_NODES, 16), BS, 0, stream>>>(rowptr, ssrc, sw, C, A, brel[3], B);

    // ---- Layer 4: 64 -> 32.  dual GEMM: y=C, r=A; fused gather -> B[N,32]
    dual_gemm_kernel<64, 32><<<blocks(N_NODES, 128), BS, 0, stream>>>(B, Wrel[4], Wroot[4], C, A);
    gather_kernel<32, true><<<blocks(N_NODES, 32), BS, 0, stream>>>(rowptr, ssrc, sw, C, A, brel[4], B);

    // ---- Fused mean pool + MLP
    pool_mlp_kernel<<<NUM_GRAPHS, 256, 0, stream>>>(B, batch, mW0, mb0, mW1, mb1, mW2, mb2, (float*)d_out);
}

// Round 5
// 375.555 us; speedup vs baseline: 7.9751x; 1.3652x over previous
//
#include <hip/hip_runtime.h>

#define N_NODES 100000
#define N_EDGES 600000
#define NUM_GRAPHS 256

#define SCAN_BS   256
#define SCAN_CH   4
#define SCAN_CHUNK (SCAN_BS * SCAN_CH)                      // 1024
#define SCAN_NB   ((N_NODES + SCAN_CHUNK - 1) / SCAN_CHUNK) // 98

// ===========================================================================
// CSR build: histogram -> 3-phase scan -> fill (once per launch, reused 5x)
// ===========================================================================
__global__ void hist_kernel(const int* __restrict__ dst, int* __restrict__ deg) {
    int e = blockIdx.x * blockDim.x + threadIdx.x;
    if (e < N_EDGES) atomicAdd(&deg[dst[e]], 1);
}

__global__ void scan_p1_kernel(const int* __restrict__ deg, int* __restrict__ bsum) {
    __shared__ int sh[SCAN_BS];
    const int b = blockIdx.x, t = threadIdx.x;
    const int base = b * SCAN_CHUNK + t * SCAN_CH;
    int s = 0;
    #pragma unroll
    for (int k = 0; k < SCAN_CH; ++k) {
        int i = base + k;
        if (i < N_NODES) s += deg[i];
    }
    sh[t] = s;
    __syncthreads();
    for (int off = SCAN_BS / 2; off > 0; off >>= 1) {
        if (t < off) sh[t] += sh[t + off];
        __syncthreads();
    }
    if (t == 0) bsum[b] = sh[0];
}

__global__ void scan_p2_kernel(int* __restrict__ bsum, int* __restrict__ rowptr) {
    __shared__ int sh[128];
    const int t = threadIdx.x;
    int v = (t < SCAN_NB) ? bsum[t] : 0;
    sh[t] = v;
    __syncthreads();
    for (int off = 1; off < 128; off <<= 1) {
        int u = (t >= off) ? sh[t - off] : 0;
        __syncthreads();
        sh[t] += u;
        __syncthreads();
    }
    if (t < SCAN_NB) bsum[t] = sh[t] - v;
    if (t == 0) rowptr[N_NODES] = N_EDGES;
}

__global__ void scan_p3_kernel(const int* __restrict__ deg, const int* __restrict__ bsum,
                               int* __restrict__ rowptr, int* __restrict__ cursor) {
    __shared__ int sh[SCAN_BS];
    const int b = blockIdx.x, t = threadIdx.x;
    const int base = b * SCAN_CHUNK + t * SCAN_CH;
    int v[SCAN_CH];
    int s = 0;
    #pragma unroll
    for (int k = 0; k < SCAN_CH; ++k) {
        int i = base + k;
        v[k] = (i < N_NODES) ? deg[i] : 0;
        s += v[k];
    }
    sh[t] = s;
    __syncthreads();
    for (int off = 1; off < SCAN_BS; off <<= 1) {
        int u = (t >= off) ? sh[t - off] : 0;
        __syncthreads();
        sh[t] += u;
        __syncthreads();
    }
    int run = bsum[b] + sh[t] - s;
    #pragma unroll
    for (int k = 0; k < SCAN_CH; ++k) {
        int i = base + k;
        if (i < N_NODES) { rowptr[i] = run; cursor[i] = run; }
        run += v[k];
    }
}

__global__ void fill_kernel(const int* __restrict__ src, const int* __restrict__ dst,
                            const float* __restrict__ w, int* __restrict__ cursor,
                            int* __restrict__ ssrc, float* __restrict__ sw) {
    int e = blockIdx.x * blockDim.x + threadIdx.x;
    if (e >= N_EDGES) return;
    int pos = atomicAdd(&cursor[dst[e]], 1);
    ssrc[pos] = src[e];
    sw[pos] = w[e];
}

// ===========================================================================
// CSR gather-aggregate (unchanged from round 4)
// ===========================================================================
template<int F, bool FUSED>
__global__ void gather_kernel(const int* __restrict__ rowptr, const int* __restrict__ ssrc,
                              const float* __restrict__ sw, const float* __restrict__ y,
                              const float* __restrict__ r, const float* __restrict__ b,
                              float* __restrict__ out) {
    constexpr int G = F / 4;
    constexpr int NPB = 256 / G;
    const int tid = threadIdx.x;
    const int c = tid % G;
    const int ln = tid / G;
    const int n = blockIdx.x * NPB + ln;
    if (n >= N_NODES) return;
    const int beg = rowptr[n], end = rowptr[n + 1];
    float4 acc = {0.f, 0.f, 0.f, 0.f};
    int i = beg;
    for (; i + 1 < end; i += 2) {
        int s0 = ssrc[i], s1 = ssrc[i + 1];
        float w0 = sw[i], w1 = sw[i + 1];
        float4 v0 = *(reinterpret_cast<const float4*>(y + (size_t)s0 * F) + c);
        float4 v1 = *(reinterpret_cast<const float4*>(y + (size_t)s1 * F) + c);
        acc.x += v0.x * w0 + v1.x * w1;
        acc.y += v0.y * w0 + v1.y * w1;
        acc.z += v0.z * w0 + v1.z * w1;
        acc.w += v0.w * w0 + v1.w * w1;
    }
    if (i < end) {
        int s0 = ssrc[i];
        float w0 = sw[i];
        float4 v0 = *(reinterpret_cast<const float4*>(y + (size_t)s0 * F) + c);
        acc.x += v0.x * w0; acc.y += v0.y * w0; acc.z += v0.z * w0; acc.w += v0.w * w0;
    }
    if constexpr (FUSED) {
        float4 rv = *(reinterpret_cast<const float4*>(r + (size_t)n * F) + c);
        float4 bv = *(reinterpret_cast<const float4*>(b) + c);
        acc.x = fmaxf(acc.x + rv.x + bv.x, 0.f);
        acc.y = fmaxf(acc.y + rv.y + bv.y, 0.f);
        acc.z = fmaxf(acc.z + rv.z + bv.z, 0.f);
        acc.w = fmaxf(acc.w + rv.w + bv.w, 0.f);
    }
    *(reinterpret_cast<float4*>(out + (size_t)n * F) + c) = acc;
}

__global__ void gather5_kernel(const int* __restrict__ rowptr, const int* __restrict__ ssrc,
                               const float* __restrict__ sw, const float* __restrict__ x,
                               float* __restrict__ agg) {
    int n = blockIdx.x * blockDim.x + threadIdx.x;
    if (n >= N_NODES) return;
    float a0 = 0.f, a1 = 0.f, a2 = 0.f, a3 = 0.f, a4 = 0.f;
    for (int i = rowptr[n]; i < rowptr[n + 1]; ++i) {
        int s = ssrc[i];
        float we = sw[i];
        const float* xs = x + (size_t)s * 5;
        a0 += xs[0] * we; a1 += xs[1] * we; a2 += xs[2] * we;
        a3 += xs[3] * we; a4 += xs[4] * we;
    }
    float* o = agg + (size_t)n * 5;
    o[0] = a0; o[1] = a1; o[2] = a2; o[3] = a3; o[4] = a4;
}

// ===========================================================================
// LDS-tiled GEMM.
//  DUAL=false (conv): out1 = relu(in1@Wrel + in2@Wroot + brel)
//  DUAL=true:         out1 = in1@Wrel ; out2 = in1@Wroot    (in2 unused)
// Block: 256 threads; per-thread tile 8 nodes x 4 outs; full-K LDS stage.
// ===========================================================================
template<int FIN, int FOUT, bool DUAL>
__global__ __launch_bounds__(256, 4)
void gemm_kernel(const float* __restrict__ in1, const float* __restrict__ in2,
                 const float* __restrict__ Wrel, const float* __restrict__ Wroot,
                 const float* __restrict__ brel,
                 float* __restrict__ out1, float* __restrict__ out2) {
    constexpr int JG = DUAL ? (FOUT / 2) : (FOUT / 4); // output float4-groups (dual: both mats)
    constexpr int NG = 256 / JG;
    constexpr int TN = NG * 8;                          // nodes per block
    constexpr int FP = FIN + 4;                         // padded LDS row (16B-aligned rows)
    constexpr int CH = FIN / 4;                         // float4 chunks per node row
    constexpr int TOT = TN * CH;

    __shared__ float smem[(DUAL ? 1 : 2) * TN * FP];
    float* S1 = smem;                                   // in1 tile
    float* S2 = smem + TN * FP;                         // in2 tile (conv only)

    const int tid = threadIdx.x;
    const int n0 = blockIdx.x * TN;
    const bool full = (n0 + TN <= N_NODES);

    // ---- stage tiles (coalesced global float4 -> aligned ds_write_b128)
    if (full) {
        #pragma unroll
        for (int r = 0; r < TOT / 256; ++r) {
            int idx = r * 256 + tid;
            int n = idx / CH, c = idx - n * CH;
            *(float4*)(S1 + n * FP + c * 4) =
                *(const float4*)(in1 + (size_t)(n0 + n) * FIN + c * 4);
            if constexpr (!DUAL)
                *(float4*)(S2 + n * FP + c * 4) =
                    *(const float4*)(in2 + (size_t)(n0 + n) * FIN + c * 4);
        }
    } else {
        #pragma unroll
        for (int r = 0; r < TOT / 256; ++r) {
            int idx = r * 256 + tid;
            int n = idx / CH, c = idx - n * CH;
            float4 z = {0.f, 0.f, 0.f, 0.f};
            bool ok = (n0 + n) < N_NODES;
            *(float4*)(S1 + n * FP + c * 4) =
                ok ? *(const float4*)(in1 + (size_t)(n0 + n) * FIN + c * 4) : z;
            if constexpr (!DUAL)
                *(float4*)(S2 + n * FP + c * 4) =
                    ok ? *(const float4*)(in2 + (size_t)(n0 + n) * FIN + c * 4) : z;
        }
    }
    __syncthreads();

    // ---- per-thread geometry
    const int jg = tid % JG;
    const int ng = tid / JG;
    const float* sA = S1 + (ng * 8) * FP;
    const float* sX = S2 + (ng * 8) * FP;

    const float* Wd = Wrel;
    float* outd = out1;
    int col;
    if constexpr (DUAL) {
        const bool second = jg >= (FOUT / 4);
        Wd = second ? Wroot : Wrel;
        outd = second ? out2 : out1;
        col = (second ? jg - FOUT / 4 : jg) * 4;
    } else {
        col = jg * 4;
    }

    float acc[8][4] = {};

    #pragma unroll 2
    for (int k0 = 0; k0 < FIN; k0 += 4) {
        float a[8][4];
        #pragma unroll
        for (int i = 0; i < 8; ++i) {
            float4 t = *(const float4*)(sA + i * FP + k0);
            a[i][0] = t.x; a[i][1] = t.y; a[i][2] = t.z; a[i][3] = t.w;
        }
        #pragma unroll
        for (int kk = 0; kk < 4; ++kk) {
            float4 w = *(const float4*)(Wd + (size_t)(k0 + kk) * FOUT + col);
            float wv[4] = {w.x, w.y, w.z, w.w};
            #pragma unroll
            for (int i = 0; i < 8; ++i)
                #pragma unroll
                for (int j = 0; j < 4; ++j)
                    acc[i][j] += a[i][kk] * wv[j];
        }
        if constexpr (!DUAL) {
            #pragma unroll
            for (int i = 0; i < 8; ++i) {
                float4 t = *(const float4*)(sX + i * FP + k0);
                a[i][0] = t.x; a[i][1] = t.y; a[i][2] = t.z; a[i][3] = t.w;
            }
            #pragma unroll
            for (int kk = 0; kk < 4; ++kk) {
                float4 w = *(const float4*)(Wroot + (size_t)(k0 + kk) * FOUT + col);
                float wv[4] = {w.x, w.y, w.z, w.w};
                #pragma unroll
                for (int i = 0; i < 8; ++i)
                    #pragma unroll
                    for (int j = 0; j < 4; ++j)
                        acc[i][j] += a[i][kk] * wv[j];
            }
        }
    }

    // ---- write
    if constexpr (DUAL) {
        #pragma unroll
        for (int i = 0; i < 8; ++i) {
            int n = n0 + ng * 8 + i;
            if (full || n < N_NODES) {
                float4 o = {acc[i][0], acc[i][1], acc[i][2], acc[i][3]};
                *(float4*)(outd + (size_t)n * FOUT + col) = o;
            }
        }
    } else {
        float4 b4 = *(const float4*)(brel + col);
        #pragma unroll
        for (int i = 0; i < 8; ++i) {
            int n = n0 + ng * 8 + i;
            if (full || n < N_NODES) {
                float4 o = {fmaxf(acc[i][0] + b4.x, 0.f), fmaxf(acc[i][1] + b4.y, 0.f),
                            fmaxf(acc[i][2] + b4.z, 0.f), fmaxf(acc[i][3] + b4.w, 0.f)};
                *(float4*)(out1 + (size_t)n * FOUT + col) = o;
            }
        }
    }
}

// ===========================================================================
// Layer-0 conv (FIN=5): keep simple register-tiled version
// ===========================================================================
template<int FIN, int FOUT>
__global__ void conv_out_kernel(const float* __restrict__ agg, const float* __restrict__ x,
                                const float* __restrict__ Wrel, const float* __restrict__ brel,
                                const float* __restrict__ Wroot, float* __restrict__ out) {
    constexpr int JG = FOUT / 4;
    constexpr int NG = 256 / JG;
    constexpr int NT = NG * 4;
    const int tid = threadIdx.x;
    const int jg = tid % JG;
    const int ng = tid / JG;
    const int n0 = blockIdx.x * NT + ng * 4;

    float acc[4][4] = {};
    for (int k = 0; k < FIN; ++k) {
        float a[4], xx[4];
        #pragma unroll
        for (int i = 0; i < 4; ++i) {
            int n = n0 + i;
            a[i]  = (n < N_NODES) ? agg[(size_t)n * FIN + k] : 0.f;
            xx[i] = (n < N_NODES) ? x[(size_t)n * FIN + k]   : 0.f;
        }
        float4 wr = *reinterpret_cast<const float4*>(Wrel  + (size_t)k * FOUT + jg * 4);
        float4 wo = *reinterpret_cast<const float4*>(Wroot + (size_t)k * FOUT + jg * 4);
        float wrv[4] = {wr.x, wr.y, wr.z, wr.w};
        float wov[4] = {wo.x, wo.y, wo.z, wo.w};
        #pragma unroll
        for (int i = 0; i < 4; ++i)
            #pragma unroll
            for (int j = 0; j < 4; ++j)
                acc[i][j] += a[i] * wrv[j] + xx[i] * wov[j];
    }
    float4 b4 = *reinterpret_cast<const float4*>(brel + jg * 4);
    float bv[4] = {b4.x, b4.y, b4.z, b4.w};
    #pragma unroll
    for (int i = 0; i < 4; ++i) {
        int n = n0 + i;
        if (n < N_NODES) {
            #pragma unroll
            for (int j = 0; j < 4; ++j)
                out[(size_t)n * FOUT + jg * 4 + j] = fmaxf(acc[i][j] + bv[j], 0.f);
        }
    }
}

// ===========================================================================
// Fused mean-pool + MLP head (batch sorted -> contiguous ranges, no atomics)
// ===========================================================================
__global__ void pool_mlp_kernel(const float* __restrict__ x, const int* __restrict__ batch,
                                const float* __restrict__ W0, const float* __restrict__ b0,
                                const float* __restrict__ W1, const float* __restrict__ b1,
                                const float* __restrict__ W2, const float* __restrict__ b2,
                                float* __restrict__ out) {
    const int g = blockIdx.x;
    auto lb = [&](int key) {
        int lo = 0, hi = N_NODES;
        while (lo < hi) {
            int mid = (lo + hi) >> 1;
            if (batch[mid] < key) lo = mid + 1; else hi = mid;
        }
        return lo;
    };
    const int beg = lb(g), end = lb(g + 1);

    const int t = threadIdx.x;
    const int q = t & 7;
    const int r = t >> 3;

    float4 s = {0.f, 0.f, 0.f, 0.f};
    for (int n = beg + r; n < end; n += 32) {
        float4 v = *(reinterpret_cast<const float4*>(x + (size_t)n * 32) + q);
        s.x += v.x; s.y += v.y; s.z += v.z; s.w += v.w;
    }
    __shared__ float4 red[32][8];
    red[r][q] = s;
    __syncthreads();

    __shared__ float h0[32], h1[32], h2[16];
    if (r == 0) {
        float4 tot = {0.f, 0.f, 0.f, 0.f};
        #pragma unroll
        for (int i = 0; i < 32; ++i) {
            float4 v = red[i][q];
            tot.x += v.x; tot.y += v.y; tot.z += v.z; tot.w += v.w;
        }
        float c = fmaxf((float)(end - beg), 1.0f);
        h0[q * 4 + 0] = tot.x / c;
        h0[q * 4 + 1] = tot.y / c;
        h0[q * 4 + 2] = tot.z / c;
        h0[q * 4 + 3] = tot.w / c;
    }
    __syncthreads();
    if (t < 32) {
        float s1 = b0[t];
        for (int k = 0; k < 32; ++k) s1 += h0[k] * W0[k * 32 + t];
        h1[t] = fmaxf(s1, 0.f);
    }
    __syncthreads();
    if (t < 16) {
        float s2 = b1[t];
        for (int k = 0; k < 32; ++k) s2 += h1[k] * W1[k * 16 + t];
        h2[t] = fmaxf(s2, 0.f);
    }
    __syncthreads();
    if (t == 0) {
        float s3 = b2[0];
        for (int k = 0; k < 16; ++k) s3 += h2[k] * W2[k];
        out[g] = s3;
    }
}

// ===========================================================================
extern "C" void kernel_launch(void* const* d_in, const int* in_sizes, int n_in,
                              void* d_out, int out_size, void* d_ws, size_t ws_size,
                              hipStream_t stream) {
    const float* x_in  = (const float*)d_in[0];
    const int*   ei    = (const int*)d_in[1];
    const int*   src   = ei;
    const int*   dst   = ei + N_EDGES;
    const float* ew    = (const float*)d_in[2];
    const int*   batch = (const int*)d_in[3];

    const float* Wrel[5]  = {(const float*)d_in[4],  (const float*)d_in[7],  (const float*)d_in[10],
                             (const float*)d_in[13], (const float*)d_in[16]};
    const float* brel[5]  = {(const float*)d_in[5],  (const float*)d_in[8],  (const float*)d_in[11],
                             (const float*)d_in[14], (const float*)d_in[17]};
    const float* Wroot[5] = {(const float*)d_in[6],  (const float*)d_in[9],  (const float*)d_in[12],
                             (const float*)d_in[15], (const float*)d_in[18]};
    const float* mW0 = (const float*)d_in[19];
    const float* mb0 = (const float*)d_in[20];
    const float* mW1 = (const float*)d_in[21];
    const float* mb1 = (const float*)d_in[22];
    const float* mW2 = (const float*)d_in[23];
    const float* mb2 = (const float*)d_in[24];

    float* ws = (float*)d_ws;
    float* A = ws;                                 // [N,64]
    float* B = A + (size_t)N_NODES * 64;           // [N,128]
    float* C = B + (size_t)N_NODES * 128;          // [N,64]
    int*   rowptr = (int*)(C + (size_t)N_NODES * 64);   // N+1
    int*   cursor = rowptr + (N_NODES + 2);             // N
    int*   deg    = cursor + N_NODES;                   // N
    int*   bsum   = deg + N_NODES;                      // SCAN_NB
    int*   ssrc   = bsum + 128;                         // E
    float* sw     = (float*)(ssrc + N_EDGES);           // E

    const int BS = 256;
    auto blocks = [](long long total, int bs) { return (int)((total + bs - 1) / bs); };

    // ---- CSR build
    hipMemsetAsync(deg, 0, N_NODES * sizeof(int), stream);
    hist_kernel<<<blocks(N_EDGES, BS), BS, 0, stream>>>(dst, deg);
    scan_p1_kernel<<<SCAN_NB, SCAN_BS, 0, stream>>>(deg, bsum);
    scan_p2_kernel<<<1, 128, 0, stream>>>(bsum, rowptr);
    scan_p3_kernel<<<SCAN_NB, SCAN_BS, 0, stream>>>(deg, bsum, rowptr, cursor);
    fill_kernel<<<blocks(N_EDGES, BS), BS, 0, stream>>>(src, dst, ew, cursor, ssrc, sw);

    // Tile-node counts: TN=64 for JG=32 kernels, TN=128 for JG=16 kernels
    const int G64  = (N_NODES + 63) / 64;    // 1563
    const int G128 = (N_NODES + 127) / 128;  // 782

    // ---- Layer 0: 5 -> 32.  gather(x_in) -> C, conv -> B[N,32]
    gather5_kernel<<<blocks(N_NODES, BS), BS, 0, stream>>>(rowptr, ssrc, sw, x_in, C);
    conv_out_kernel<5, 32><<<blocks(N_NODES, 128), BS, 0, stream>>>(C, x_in, Wrel[0], brel[0], Wroot[0], B);

    // ---- Layer 1: 32 -> 64.  gather(B,w32) -> C, LDS-GEMM -> A[N,64]
    gather_kernel<32, false><<<blocks(N_NODES, 32), BS, 0, stream>>>(rowptr, ssrc, sw, B, nullptr, nullptr, C);
    gemm_kernel<32, 64, false><<<G128, 256, 0, stream>>>(C, B, Wrel[1], Wroot[1], brel[1], A, nullptr);

    // ---- Layer 2: 64 -> 128. gather(A,w64) -> C, LDS-GEMM -> B[N,128]
    gather_kernel<64, false><<<blocks(N_NODES, 16), BS, 0, stream>>>(rowptr, ssrc, sw, A, nullptr, nullptr, C);
    gemm_kernel<64, 128, false><<<G64, 256, 0, stream>>>(C, A, Wrel[2], Wroot[2], brel[2], B, nullptr);

    // ---- Layer 3: 128 -> 64. dual LDS-GEMM: y=C, r=A; fused gather -> B[N,64]
    gemm_kernel<128, 64, true><<<G64, 256, 0, stream>>>(B, nullptr, Wrel[3], Wroot[3], nullptr, C, A);
    gather_kernel<64, true><<<blocks(N_NODES, 16), BS, 0, stream>>>(rowptr, ssrc, sw, C, A, brel[3], B);

    // ---- Layer 4: 64 -> 32.  dual LDS-GEMM: y=C, r=A; fused gather -> B[N,32]
    gemm_kernel<64, 32, true><<<G128, 256, 0, stream>>>(B, nullptr, Wrel[4], Wroot[4], nullptr, C, A);
    gather_kernel<32, true><<<blocks(N_NODES, 32), BS, 0, stream>>>(rowptr, ssrc, sw, C, A, brel[4], B);

    // ---- Fused mean pool + MLP
    pool_mlp_kernel<<<NUM_GRAPHS, 256, 0, stream>>>(B, batch, mW0, mb0, mW1, mb1, mW2, mb2, (float*)d_out);
}